// Round 4
// baseline (209.550 us; speedup 1.0000x reference)
//
#include <hip/hip_runtime.h>
#include <hip/hip_bf16.h>

#define TCH 512
#define MTOT 16384
#define SEQ 2048
#define LN_EPS 1e-5f

typedef __attribute__((ext_vector_type(8))) __bf16 bf16x8;
typedef __attribute__((ext_vector_type(4))) float f32x4;

__device__ __forceinline__ unsigned pkbf(float a, float b) {
  union { __hip_bfloat16 h; unsigned short u; } ca, cb;
  ca.h = __float2bfloat16(a); cb.h = __float2bfloat16(b);
  return (unsigned)ca.u | ((unsigned)cb.u << 16);
}
__device__ __forceinline__ float bf_lo(unsigned u) { return __uint_as_float(u << 16); }
__device__ __forceinline__ float bf_hi(unsigned u) { return __uint_as_float(u & 0xffff0000u); }

__device__ __forceinline__ bf16x8 cvt8(float4 a, float4 b) {
  union { __hip_bfloat16 h; __bf16 v; } u;
  bf16x8 r;
  u.h = __float2bfloat16(a.x); r[0] = u.v;
  u.h = __float2bfloat16(a.y); r[1] = u.v;
  u.h = __float2bfloat16(a.z); r[2] = u.v;
  u.h = __float2bfloat16(a.w); r[3] = u.v;
  u.h = __float2bfloat16(b.x); r[4] = u.v;
  u.h = __float2bfloat16(b.y); r[5] = u.v;
  u.h = __float2bfloat16(b.z); r[6] = u.v;
  u.h = __float2bfloat16(b.w); r[7] = u.v;
  return r;
}

// log2(e)/sqrt(3): folded into wq/bq so attention uses exp2 directly
#define QSCALE 0.8329517853860118f

// ---------------- prep ------------------------------------------------------
__global__ __launch_bounds__(256) void prep_kernel(
    const float* __restrict__ w2,
    const float* __restrict__ wo, const float* __restrict__ bo,
    const float* __restrict__ wq, const float* __restrict__ bq,
    const float* __restrict__ wk, const float* __restrict__ bk,
    const float* __restrict__ wv, const float* __restrict__ bv,
    __hip_bfloat16* __restrict__ w2b,
    float4* __restrict__ wo_eff4,
    __hip_bfloat16* __restrict__ wqkvb, float* __restrict__ qkvbias)
{
  int i = blockIdx.x * 256 + threadIdx.x;   // grid covers 512*512 exactly
  w2b[i] = __float2bfloat16(w2[i]);
  if (i < TCH) {
    float s0 = 0.f, s1 = 0.f, s2 = 0.f;
    #pragma unroll
    for (int h = 0; h < 6; ++h) {
      s0 += wo[i*18 + h*3 + 0];
      s1 += wo[i*18 + h*3 + 1];
      s2 += wo[i*18 + h*3 + 2];
    }
    wo_eff4[i] = make_float4(s0, s1, s2, bo[i]);
  }
  if (i < 16 * TCH) {
    int row = i >> 9, k = i & 511;
    float v;
    if      (row < 3) v = wq[row * TCH + k] * QSCALE;
    else if (row < 6) v = wk[(row - 3) * TCH + k];
    else if (row < 9) v = wv[(row - 6) * TCH + k];
    else              v = 0.f;
    wqkvb[i] = __float2bfloat16(v);
  }
  if (i < 16) {
    float v;
    if      (i < 3) v = bq[i] * QSCALE;
    else if (i < 6) v = bk[i - 3];
    else if (i < 9) v = bv[i - 6];
    else            v = 0.f;
    qkvbias[i] = v;
  }
}

// ---------------- prep2: fold w1 through wo_eff -----------------------------
// weff4[i] = sum_k w1[i,k] * wo_eff4[k]  (+ b1[i] into .w, since .w carries bo)
__global__ __launch_bounds__(256) void prep2_kernel(
    const float* __restrict__ w1, const float* __restrict__ b1,
    const float4* __restrict__ wo_eff4, float4* __restrict__ weff4)
{
  const int t = threadIdx.x, w = t >> 6, l = t & 63;
  const int i = blockIdx.x * 4 + w;         // 128 blocks * 4 waves = 512 rows
  float sx = 0.f, sy = 0.f, sz = 0.f, sw = 0.f;
  #pragma unroll
  for (int j = 0; j < 8; ++j) {
    const int k = j * 64 + l;
    const float a = w1[(size_t)i * TCH + k];
    const float4 e = wo_eff4[k];
    sx += a * e.x; sy += a * e.y; sz += a * e.z; sw += a * e.w;
  }
  #pragma unroll
  for (int off = 1; off < 64; off <<= 1) {
    sx += __shfl_xor(sx, off, 64);
    sy += __shfl_xor(sy, off, 64);
    sz += __shfl_xor(sz, off, 64);
    sw += __shfl_xor(sw, off, 64);
  }
  if (l == 0) weff4[i] = make_float4(sx, sy, sz, sw + b1[i]);
}

// ---------------- qkv via MFMA (split-K across waves) -----------------------
__global__ __launch_bounds__(256) void qkv_kernel(
    const float* __restrict__ x,
    const __hip_bfloat16* __restrict__ wqkvb, const float* __restrict__ qkvbias,
    float4* __restrict__ q4, uint4* __restrict__ kvp)
{
  const int t = threadIdx.x, wv = t >> 6, ln = t & 63;
  const int l16 = ln & 15, quad = ln >> 4;
  const int row0 = blockIdx.x * 16;
  const int k0 = wv * 128;

  bf16x8 bfr[4];
  #pragma unroll
  for (int ks = 0; ks < 4; ++ks)
    bfr[ks] = *reinterpret_cast<const bf16x8*>(wqkvb + l16 * TCH + k0 + ks * 32 + quad * 8);

  const float* xp = x + (size_t)(row0 + l16) * TCH + k0 + quad * 8;

  f32x4 acc = {};
  #pragma unroll
  for (int ks = 0; ks < 4; ++ks) {
    float4 a = *(const float4*)(xp + ks * 32);
    float4 b = *(const float4*)(xp + ks * 32 + 4);
    acc = __builtin_amdgcn_mfma_f32_16x16x32_bf16(cvt8(a, b), bfr[ks], acc, 0, 0, 0);
  }

  __shared__ float tr[4][16][17];
  __shared__ float fin[16][17];
  #pragma unroll
  for (int r = 0; r < 4; ++r) tr[wv][quad * 4 + r][l16] = acc[r];
  __syncthreads();

  {
    const int r = t >> 4, c = t & 15;        // 256 threads cover 16x16
    fin[r][c] = tr[0][r][c] + tr[1][r][c] + tr[2][r][c] + tr[3][r][c] + qkvbias[c];
  }
  __syncthreads();

  if (t < 16) {
    q4[row0 + t] = make_float4(fin[t][0], fin[t][1], fin[t][2], 0.f);  // pre-scaled
  } else if (t < 32) {
    const int r = t - 16;
    kvp[row0 + r] = make_uint4(pkbf(fin[r][3], fin[r][4]),
                               pkbf(fin[r][5], fin[r][6]),
                               pkbf(fin[r][7], fin[r][8]), 0u);
  }
}

// ---------------- attention + rank-3 r0 + LN1 (fused) ----------------------
// r0 = x + z @ weff^T + beff ; r1 = LN(r0). Each block owns 64 full rows.
__global__ __launch_bounds__(1024) void attn_kernel(
    const float4* __restrict__ q4, const uint4* __restrict__ kvp,
    const float* __restrict__ x, const float4* __restrict__ weff4,
    const float* __restrict__ gamma, const float* __restrict__ beta,
    __hip_bfloat16* __restrict__ r0b, __hip_bfloat16* __restrict__ r1b)
{
  __shared__ float4 part[16 * 64];  // 16 KB
  __shared__ float4 zbuf[64];       // 1 KB

  const int b    = blockIdx.x >> 5;
  const int qc   = blockIdx.x & 31;
  const int base = b * SEQ;
  const int tid  = threadIdx.x;
  const int wave = tid >> 6;
  const int lane = tid & 63;
  const float4 q = q4[base + qc * 64 + lane];   // pre-scaled by log2e/sqrt(3)

  const int wu = __builtin_amdgcn_readfirstlane(wave);
  const uint4* kvw = kvp + base + wu * 128;     // wave-uniform -> s_load

  float l[4] = {}, a0[4] = {}, a1[4] = {}, a2[4] = {};
  #pragma unroll 4
  for (int i = 0; i < 32; ++i) {
    #pragma unroll
    for (int s = 0; s < 4; ++s) {               // 4 independent chains
      uint4 rec = kvw[s * 32 + i];
      float sc = bf_lo(rec.x) * q.x + bf_hi(rec.x) * q.y + bf_lo(rec.y) * q.z;
      float p = __builtin_amdgcn_exp2f(sc);
      l[s]  += p;
      a0[s] += p * bf_hi(rec.y);
      a1[s] += p * bf_lo(rec.z);
      a2[s] += p * bf_hi(rec.z);
    }
  }
  part[wave * 64 + lane] = make_float4(l[0]+l[1]+l[2]+l[3],
                                       a0[0]+a0[1]+a0[2]+a0[3],
                                       a1[0]+a1[1]+a1[2]+a1[3],
                                       a2[0]+a2[1]+a2[2]+a2[3]);
  __syncthreads();

  if (tid < 64) {
    float L = 0.f, A0 = 0.f, A1 = 0.f, A2 = 0.f;
    #pragma unroll
    for (int w = 0; w < 16; ++w) {
      float4 p = part[w * 64 + tid];
      L += p.x; A0 += p.y; A1 += p.z; A2 += p.w;
    }
    const float inv = 1.f / L;
    zbuf[tid] = make_float4(A0 * inv, A1 * inv, A2 * inv, 0.f);
  }
  __syncthreads();

  // ---- epilogue: each wave handles 4 full rows (16 waves * 4 = 64 rows) ----
  const int c0 = lane * 8;
  float4 wv[8];
  #pragma unroll
  for (int j = 0; j < 8; ++j) wv[j] = weff4[c0 + j];   // (weff0..2, beff)
  const float4 g0  = *(const float4*)(gamma + c0);
  const float4 g1  = *(const float4*)(gamma + c0 + 4);
  const float4 be0 = *(const float4*)(beta  + c0);
  const float4 be1 = *(const float4*)(beta  + c0 + 4);
  const float gg[8] = {g0.x,g0.y,g0.z,g0.w,g1.x,g1.y,g1.z,g1.w};
  const float bb[8] = {be0.x,be0.y,be0.z,be0.w,be1.x,be1.y,be1.z,be1.w};

  #pragma unroll
  for (int qi = 0; qi < 4; ++qi) {
    const int qloc = wave * 4 + qi;
    const int grow = base + qc * 64 + qloc;
    const float4 z = zbuf[qloc];
    const float* xr = x + (size_t)grow * TCH + c0;
    const float4 x0 = *(const float4*)xr;
    const float4 x1 = *(const float4*)(xr + 4);
    const float xv[8] = {x0.x,x0.y,x0.z,x0.w,x1.x,x1.y,x1.z,x1.w};
    float r0v[8], s = 0.f, sq = 0.f;
    #pragma unroll
    for (int j = 0; j < 8; ++j) {
      float v = xv[j] + z.x * wv[j].x + z.y * wv[j].y + z.z * wv[j].z + wv[j].w;
      r0v[j] = v; s += v; sq += v * v;
    }
    #pragma unroll
    for (int off = 1; off < 64; off <<= 1) {
      s  += __shfl_xor(s,  off, 64);
      sq += __shfl_xor(sq, off, 64);
    }
    const float mu = s * (1.f / TCH);
    const float rs = rsqrtf(sq * (1.f / TCH) - mu * mu + LN_EPS);
    *(bf16x8*)(r0b + (size_t)grow * TCH + c0) =
        cvt8(make_float4(r0v[0], r0v[1], r0v[2], r0v[3]),
             make_float4(r0v[4], r0v[5], r0v[6], r0v[7]));
    float r1v[8];
    #pragma unroll
    for (int j = 0; j < 8; ++j) r1v[j] = (r0v[j] - mu) * rs * gg[j] + bb[j];
    *(bf16x8*)(r1b + (size_t)grow * TCH + c0) =
        cvt8(make_float4(r1v[0], r1v[1], r1v[2], r1v[3]),
             make_float4(r1v[4], r1v[5], r1v[6], r1v[7]));
  }
}

// ---------------- GEMM2 (v3: LDS-free, direct fragment loads) ---------------
// out = LN(r0 + r1 @ w2^T + b2). 512 blocks x 512 thr (8 waves);
// block = 32 rows x 512 cols; wave = 16 rows x 128 cols.
// MFMA fragments are 16B/lane contiguous in k -> load straight from global.
// No LDS staging, no barriers in the K-loop: compiler software-pipelines.
__global__ __launch_bounds__(512) void gemm2_kernel(
    const __hip_bfloat16* __restrict__ A,    // r1b [16384,512]
    const __hip_bfloat16* __restrict__ W,    // w2b [512,512], row = out col
    const float* __restrict__ bias,          // b2
    const __hip_bfloat16* __restrict__ res,  // r0b
    const float* __restrict__ gamma, const float* __restrict__ beta,
    float* __restrict__ out)
{
  __shared__ float redS[32][4], redQ[32][4];
  __shared__ float muL[32], rsL[32];

  const int row0 = blockIdx.x * 32;
  const int t    = threadIdx.x;
  const int w    = t >> 6;                  // 0..7
  const int l    = t & 63;
  const int l16  = l & 15, quad = l >> 4;
  const int wr   = w >> 2, wc = w & 3;      // wave tile: 16 rows x 128 cols

  // per-lane fragment base pointers (k advances by 32 elems = 64 B per step)
  const __hip_bfloat16* Ap = A + (size_t)(row0 + wr * 16 + l16) * TCH + quad * 8;
  const __hip_bfloat16* Wp = W + (size_t)(wc * 128 + l16) * TCH + quad * 8;

  f32x4 acc[8] = {};
  #pragma unroll
  for (int ks = 0; ks < 16; ++ks) {
    bf16x8 af = *reinterpret_cast<const bf16x8*>(Ap + ks * 32);
    #pragma unroll
    for (int n = 0; n < 8; ++n) {
      bf16x8 bfv = *reinterpret_cast<const bf16x8*>(Wp + (size_t)n * 16 * TCH + ks * 32);
      acc[n] = __builtin_amdgcn_mfma_f32_16x16x32_bf16(af, bfv, acc[n], 0, 0, 0);
    }
  }

  // epilogue: v = acc + b2 + r0 ; row stats ; then LN2 -> out (fp32)
  #pragma unroll
  for (int r = 0; r < 4; ++r) {
    const int lrow = wr * 16 + quad * 4 + r;
    const int grow = row0 + lrow;
    float s = 0.f, sq = 0.f;
    #pragma unroll
    for (int n = 0; n < 8; ++n) {
      const int col = wc * 128 + n * 16 + l16;
      float v = acc[n][r] + bias[col] +
                __bfloat162float(res[(size_t)grow * TCH + col]);
      acc[n][r] = v; s += v; sq += v * v;
    }
    #pragma unroll
    for (int off = 1; off < 16; off <<= 1) {   // reduce across l16 group
      s  += __shfl_xor(s,  off, 64);
      sq += __shfl_xor(sq, off, 64);
    }
    if (l16 == 0) { redS[lrow][wc] = s; redQ[lrow][wc] = sq; }
  }
  __syncthreads();
  if (t < 32) {
    const float S = redS[t][0] + redS[t][1] + redS[t][2] + redS[t][3];
    const float Q = redQ[t][0] + redQ[t][1] + redQ[t][2] + redQ[t][3];
    const float mu = S * (1.f / TCH);
    muL[t] = mu;
    rsL[t] = rsqrtf(Q * (1.f / TCH) - mu * mu + LN_EPS);
  }
  __syncthreads();
  #pragma unroll
  for (int r = 0; r < 4; ++r) {
    const int lrow = wr * 16 + quad * 4 + r;
    const int grow = row0 + lrow;
    const float mu = muL[lrow], rs = rsL[lrow];
    #pragma unroll
    for (int n = 0; n < 8; ++n) {
      const int col = wc * 128 + n * 16 + l16;
      out[(size_t)grow * TCH + col] =
          (acc[n][r] - mu) * rs * gamma[col] + beta[col];
    }
  }
}

// ---------------- host ------------------------------------------------------
extern "C" void kernel_launch(void* const* d_in, const int* in_sizes, int n_in,
                              void* d_out, int out_size, void* d_ws, size_t ws_size,
                              hipStream_t stream) {
  (void)in_sizes; (void)n_in; (void)out_size; (void)ws_size;
  const float* x     = (const float*)d_in[0];
  const float* wq    = (const float*)d_in[1];
  const float* bq    = (const float*)d_in[2];
  const float* wk    = (const float*)d_in[3];
  const float* bk    = (const float*)d_in[4];
  const float* wv    = (const float*)d_in[5];
  const float* bv    = (const float*)d_in[6];
  const float* wo    = (const float*)d_in[7];
  const float* bo    = (const float*)d_in[8];
  const float* w1    = (const float*)d_in[9];
  const float* b1    = (const float*)d_in[10];
  const float* w2    = (const float*)d_in[11];
  const float* b2    = (const float*)d_in[12];
  const float* gamma = (const float*)d_in[13];
  const float* beta  = (const float*)d_in[14];
  float* out = (float*)d_out;

  char* ws = (char*)d_ws;
  size_t off = 0;
  float4* q4      = (float4*)(ws + off); off += (size_t)MTOT * 16;
  uint4*  kvp     = (uint4*)(ws + off);  off += (size_t)MTOT * 16;
  float4* wo_eff4 = (float4*)(ws + off); off += (size_t)TCH * 16;
  float4* weff4   = (float4*)(ws + off); off += (size_t)TCH * 16;
  __hip_bfloat16* w2b   = (__hip_bfloat16*)(ws + off); off += (size_t)TCH * TCH * 2;
  __hip_bfloat16* wqkvb = (__hip_bfloat16*)(ws + off); off += (size_t)16 * TCH * 2;
  float*          qkvbias = (float*)(ws + off);        off += 64;
  __hip_bfloat16* r0b = (__hip_bfloat16*)(ws + off); off += (size_t)MTOT * TCH * 2;  // 16 MB
  __hip_bfloat16* r1b = (__hip_bfloat16*)(ws + off); off += (size_t)MTOT * TCH * 2;  // 16 MB

  prep_kernel<<<(TCH*TCH)/256, 256, 0, stream>>>(
      w2, wo, bo, wq, bq, wk, bk, wv, bv, w2b, wo_eff4, wqkvb, qkvbias);
  prep2_kernel<<<TCH/4, 256, 0, stream>>>(w1, b1, wo_eff4, weff4);
  qkv_kernel<<<MTOT/16, 256, 0, stream>>>(x, wqkvb, qkvbias, q4, kvp);
  // r0 = x + z @ weff^T + beff ; r1 = LN(r0)   (attention fused)
  attn_kernel<<<MTOT/64, 1024, 0, stream>>>(q4, kvp, x, weff4, gamma, beta, r0b, r1b);
  // out = LN(r0 + r1 @ w2^T + b2)              (GEMM + LN2 fused)
  gemm2_kernel<<<MTOT/32, 512, 0, stream>>>(r1b, w2b, b2, r0b, gamma, beta, out);
}

// Round 6
// 178.119 us; speedup vs baseline: 1.1765x; 1.1765x over previous
//
#include <hip/hip_runtime.h>
#include <hip/hip_bf16.h>

#define TCH 512
#define MTOT 16384
#define SEQ 2048
#define LN_EPS 1e-5f

typedef __attribute__((ext_vector_type(8))) __bf16 bf16x8;
typedef __attribute__((ext_vector_type(4))) float f32x4;

__device__ __forceinline__ unsigned pkbf(float a, float b) {
  union { __hip_bfloat16 h; unsigned short u; } ca, cb;
  ca.h = __float2bfloat16(a); cb.h = __float2bfloat16(b);
  return (unsigned)ca.u | ((unsigned)cb.u << 16);
}
__device__ __forceinline__ float bf_lo(unsigned u) { return __uint_as_float(u << 16); }
__device__ __forceinline__ float bf_hi(unsigned u) { return __uint_as_float(u & 0xffff0000u); }

__device__ __forceinline__ bf16x8 cvt8(float4 a, float4 b) {
  union { __hip_bfloat16 h; __bf16 v; } u;
  bf16x8 r;
  u.h = __float2bfloat16(a.x); r[0] = u.v;
  u.h = __float2bfloat16(a.y); r[1] = u.v;
  u.h = __float2bfloat16(a.z); r[2] = u.v;
  u.h = __float2bfloat16(a.w); r[3] = u.v;
  u.h = __float2bfloat16(b.x); r[4] = u.v;
  u.h = __float2bfloat16(b.y); r[5] = u.v;
  u.h = __float2bfloat16(b.z); r[6] = u.v;
  u.h = __float2bfloat16(b.w); r[7] = u.v;
  return r;
}

// log2(e)/sqrt(3): folded into wq/bq so attention uses exp2 directly
#define QSCALE 0.8329517853860118f

// ---------------- prep ------------------------------------------------------
__global__ __launch_bounds__(256) void prep_kernel(
    const float* __restrict__ w2,
    const float* __restrict__ wo, const float* __restrict__ bo,
    const float* __restrict__ wq, const float* __restrict__ bq,
    const float* __restrict__ wk, const float* __restrict__ bk,
    const float* __restrict__ wv, const float* __restrict__ bv,
    __hip_bfloat16* __restrict__ w2b,
    float4* __restrict__ wo_eff4,
    __hip_bfloat16* __restrict__ wqkvb, float* __restrict__ qkvbias)
{
  int i = blockIdx.x * 256 + threadIdx.x;   // grid covers 512*512 exactly
  w2b[i] = __float2bfloat16(w2[i]);
  if (i < TCH) {
    float s0 = 0.f, s1 = 0.f, s2 = 0.f;
    #pragma unroll
    for (int h = 0; h < 6; ++h) {
      s0 += wo[i*18 + h*3 + 0];
      s1 += wo[i*18 + h*3 + 1];
      s2 += wo[i*18 + h*3 + 2];
    }
    wo_eff4[i] = make_float4(s0, s1, s2, bo[i]);
  }
  if (i < 16 * TCH) {
    int row = i >> 9, k = i & 511;
    float v;
    if      (row < 3) v = wq[row * TCH + k] * QSCALE;
    else if (row < 6) v = wk[(row - 3) * TCH + k];
    else if (row < 9) v = wv[(row - 6) * TCH + k];
    else              v = 0.f;
    wqkvb[i] = __float2bfloat16(v);
  }
  if (i < 16) {
    float v;
    if      (i < 3) v = bq[i] * QSCALE;
    else if (i < 6) v = bk[i - 3];
    else if (i < 9) v = bv[i - 6];
    else            v = 0.f;
    qkvbias[i] = v;
  }
}

// ---------------- prep2: fold w1 through wo_eff -----------------------------
// weff4[i] = sum_k w1[i,k] * wo_eff4[k]  (+ b1[i] into .w, since .w carries bo)
__global__ __launch_bounds__(256) void prep2_kernel(
    const float* __restrict__ w1, const float* __restrict__ b1,
    const float4* __restrict__ wo_eff4, float4* __restrict__ weff4)
{
  const int t = threadIdx.x, w = t >> 6, l = t & 63;
  const int i = blockIdx.x * 4 + w;         // 128 blocks * 4 waves = 512 rows
  float sx = 0.f, sy = 0.f, sz = 0.f, sw = 0.f;
  #pragma unroll
  for (int j = 0; j < 8; ++j) {
    const int k = j * 64 + l;
    const float a = w1[(size_t)i * TCH + k];
    const float4 e = wo_eff4[k];
    sx += a * e.x; sy += a * e.y; sz += a * e.z; sw += a * e.w;
  }
  #pragma unroll
  for (int off = 1; off < 64; off <<= 1) {
    sx += __shfl_xor(sx, off, 64);
    sy += __shfl_xor(sy, off, 64);
    sz += __shfl_xor(sz, off, 64);
    sw += __shfl_xor(sw, off, 64);
  }
  if (l == 0) weff4[i] = make_float4(sx, sy, sz, sw + b1[i]);
}

// ---------------- qkv via MFMA (split-K across waves) -----------------------
__global__ __launch_bounds__(256) void qkv_kernel(
    const float* __restrict__ x,
    const __hip_bfloat16* __restrict__ wqkvb, const float* __restrict__ qkvbias,
    float4* __restrict__ q4, uint4* __restrict__ kvp)
{
  const int t = threadIdx.x, wv = t >> 6, ln = t & 63;
  const int l16 = ln & 15, quad = ln >> 4;
  const int row0 = blockIdx.x * 16;
  const int k0 = wv * 128;

  bf16x8 bfr[4];
  #pragma unroll
  for (int ks = 0; ks < 4; ++ks)
    bfr[ks] = *reinterpret_cast<const bf16x8*>(wqkvb + l16 * TCH + k0 + ks * 32 + quad * 8);

  const float* xp = x + (size_t)(row0 + l16) * TCH + k0 + quad * 8;

  f32x4 acc = {};
  #pragma unroll
  for (int ks = 0; ks < 4; ++ks) {
    float4 a = *(const float4*)(xp + ks * 32);
    float4 b = *(const float4*)(xp + ks * 32 + 4);
    acc = __builtin_amdgcn_mfma_f32_16x16x32_bf16(cvt8(a, b), bfr[ks], acc, 0, 0, 0);
  }

  __shared__ float tr[4][16][17];
  __shared__ float fin[16][17];
  #pragma unroll
  for (int r = 0; r < 4; ++r) tr[wv][quad * 4 + r][l16] = acc[r];
  __syncthreads();

  {
    const int r = t >> 4, c = t & 15;        // 256 threads cover 16x16
    fin[r][c] = tr[0][r][c] + tr[1][r][c] + tr[2][r][c] + tr[3][r][c] + qkvbias[c];
  }
  __syncthreads();

  if (t < 16) {
    q4[row0 + t] = make_float4(fin[t][0], fin[t][1], fin[t][2], 0.f);  // pre-scaled
  } else if (t < 32) {
    const int r = t - 16;
    kvp[row0 + r] = make_uint4(pkbf(fin[r][3], fin[r][4]),
                               pkbf(fin[r][5], fin[r][6]),
                               pkbf(fin[r][7], fin[r][8]), 0u);
  }
}

// ---------------- attention + rank-3 r0 + LN1 (fused) ----------------------
// r0 = x + z @ weff^T + beff ; r1 = LN(r0). Each block owns 64 full rows.
__global__ __launch_bounds__(1024) void attn_kernel(
    const float4* __restrict__ q4, const uint4* __restrict__ kvp,
    const float* __restrict__ x, const float4* __restrict__ weff4,
    const float* __restrict__ gamma, const float* __restrict__ beta,
    __hip_bfloat16* __restrict__ r0b, __hip_bfloat16* __restrict__ r1b)
{
  __shared__ float4 part[16 * 64];  // 16 KB
  __shared__ float4 zbuf[64];       // 1 KB

  const int b    = blockIdx.x >> 5;
  const int qc   = blockIdx.x & 31;
  const int base = b * SEQ;
  const int tid  = threadIdx.x;
  const int wave = tid >> 6;
  const int lane = tid & 63;
  const float4 q = q4[base + qc * 64 + lane];   // pre-scaled by log2e/sqrt(3)

  const int wu = __builtin_amdgcn_readfirstlane(wave);
  const uint4* kvw = kvp + base + wu * 128;     // wave-uniform -> s_load

  float l[4] = {}, a0[4] = {}, a1[4] = {}, a2[4] = {};
  #pragma unroll 4
  for (int i = 0; i < 32; ++i) {
    #pragma unroll
    for (int s = 0; s < 4; ++s) {               // 4 independent chains
      uint4 rec = kvw[s * 32 + i];
      float sc = bf_lo(rec.x) * q.x + bf_hi(rec.x) * q.y + bf_lo(rec.y) * q.z;
      float p = __builtin_amdgcn_exp2f(sc);
      l[s]  += p;
      a0[s] += p * bf_hi(rec.y);
      a1[s] += p * bf_lo(rec.z);
      a2[s] += p * bf_hi(rec.z);
    }
  }
  part[wave * 64 + lane] = make_float4(l[0]+l[1]+l[2]+l[3],
                                       a0[0]+a0[1]+a0[2]+a0[3],
                                       a1[0]+a1[1]+a1[2]+a1[3],
                                       a2[0]+a2[1]+a2[2]+a2[3]);
  __syncthreads();

  if (tid < 64) {
    float L = 0.f, A0 = 0.f, A1 = 0.f, A2 = 0.f;
    #pragma unroll
    for (int w = 0; w < 16; ++w) {
      float4 p = part[w * 64 + tid];
      L += p.x; A0 += p.y; A1 += p.z; A2 += p.w;
    }
    const float inv = 1.f / L;
    zbuf[tid] = make_float4(A0 * inv, A1 * inv, A2 * inv, 0.f);
  }
  __syncthreads();

  // ---- epilogue: each wave handles 4 full rows (16 waves * 4 = 64 rows) ----
  const int c0 = lane * 8;
  float4 wv[8];
  #pragma unroll
  for (int j = 0; j < 8; ++j) wv[j] = weff4[c0 + j];   // (weff0..2, beff)
  const float4 g0  = *(const float4*)(gamma + c0);
  const float4 g1  = *(const float4*)(gamma + c0 + 4);
  const float4 be0 = *(const float4*)(beta  + c0);
  const float4 be1 = *(const float4*)(beta  + c0 + 4);
  const float gg[8] = {g0.x,g0.y,g0.z,g0.w,g1.x,g1.y,g1.z,g1.w};
  const float bb[8] = {be0.x,be0.y,be0.z,be0.w,be1.x,be1.y,be1.z,be1.w};

  #pragma unroll
  for (int qi = 0; qi < 4; ++qi) {
    const int qloc = wave * 4 + qi;
    const int grow = base + qc * 64 + qloc;
    const float4 z = zbuf[qloc];
    const float* xr = x + (size_t)grow * TCH + c0;
    const float4 x0 = *(const float4*)xr;
    const float4 x1 = *(const float4*)(xr + 4);
    const float xv[8] = {x0.x,x0.y,x0.z,x0.w,x1.x,x1.y,x1.z,x1.w};
    float r0v[8], s = 0.f, sq = 0.f;
    #pragma unroll
    for (int j = 0; j < 8; ++j) {
      float v = xv[j] + z.x * wv[j].x + z.y * wv[j].y + z.z * wv[j].z + wv[j].w;
      r0v[j] = v; s += v; sq += v * v;
    }
    #pragma unroll
    for (int off = 1; off < 64; off <<= 1) {
      s  += __shfl_xor(s,  off, 64);
      sq += __shfl_xor(sq, off, 64);
    }
    const float mu = s * (1.f / TCH);
    const float rs = rsqrtf(sq * (1.f / TCH) - mu * mu + LN_EPS);
    *(bf16x8*)(r0b + (size_t)grow * TCH + c0) =
        cvt8(make_float4(r0v[0], r0v[1], r0v[2], r0v[3]),
             make_float4(r0v[4], r0v[5], r0v[6], r0v[7]));
    float r1v[8];
    #pragma unroll
    for (int j = 0; j < 8; ++j) r1v[j] = (r0v[j] - mu) * rs * gg[j] + bb[j];
    *(bf16x8*)(r1b + (size_t)grow * TCH + c0) =
        cvt8(make_float4(r1v[0], r1v[1], r1v[2], r1v[3]),
             make_float4(r1v[4], r1v[5], r1v[6], r1v[7]));
  }
}

// ---------------- GEMM 128x128 (m97 structure) + bias + residual ------------
// 512 blocks x 256 thr (4 waves). rb = bx&127 (rows), cb = bx>>7 (cols):
// the 4 col-blocks sharing an A-tile map to the same XCD (128 % 8 == 0).
// Double-buffered global_load_lds staging; per-block row partial sums out.
__global__ __launch_bounds__(256) void gemm_kernel(
    const __hip_bfloat16* __restrict__ A,   // [16384, 512]
    const __hip_bfloat16* __restrict__ W,   // [512, 512], row = out col
    const float* __restrict__ bias,
    const __hip_bfloat16* __restrict__ res, // [16384, 512]
    __hip_bfloat16* __restrict__ Cout,      // res + A@W^T + bias
    float2* __restrict__ partial)           // [4][16384] (sum, sumsq)
{
  __shared__ __align__(16) __hip_bfloat16 At[2][4][128][8];  // 16 KB
  __shared__ __align__(16) __hip_bfloat16 Wt[2][4][128][8];  // 16 KB
  __shared__ float redS[128][2];
  __shared__ float redQ[128][2];

  const int bx   = blockIdx.x;
  const int rb   = bx & 127, cb = bx >> 7;
  const int row0 = rb * 128, col0 = cb * 128;
  const int t    = threadIdx.x;
  const int w    = t >> 6, l = t & 63;
  const int l16  = l & 15, quad = l >> 4;
  const int wr   = w >> 1, wc = w & 1;
  const int srow = t & 127;                 // staging row
  const int sq0  = (t >> 7) << 1;           // staging quad base (wave-uniform)

  auto stage = [&](int ks, int b) {
    #pragma unroll
    for (int j = 0; j < 2; ++j) {
      const int q = sq0 | j;
      __builtin_amdgcn_global_load_lds(
          (const __attribute__((address_space(1))) void*)(A + (size_t)(row0 + srow) * TCH + ks * 32 + q * 8),
          (__attribute__((address_space(3))) void*)&At[b][q][srow][0], 16, 0, 0);
      __builtin_amdgcn_global_load_lds(
          (const __attribute__((address_space(1))) void*)(W + (size_t)(col0 + srow) * TCH + ks * 32 + q * 8),
          (__attribute__((address_space(3))) void*)&Wt[b][q][srow][0], 16, 0, 0);
    }
  };

  f32x4 acc[4][4] = {};
  stage(0, 0);
  for (int ks = 0; ks < 16; ++ks) {
    const int cur = ks & 1;
    __syncthreads();
    if (ks < 15) stage(ks + 1, cur ^ 1);
    bf16x8 af[4], bf[4];
    #pragma unroll
    for (int mt = 0; mt < 4; ++mt)
      af[mt] = *reinterpret_cast<const bf16x8*>(&At[cur][quad][wr * 64 + mt * 16 + l16][0]);
    #pragma unroll
    for (int nt = 0; nt < 4; ++nt)
      bf[nt] = *reinterpret_cast<const bf16x8*>(&Wt[cur][quad][wc * 64 + nt * 16 + l16][0]);
    #pragma unroll
    for (int mt = 0; mt < 4; ++mt)
      #pragma unroll
      for (int nt = 0; nt < 4; ++nt)
        acc[mt][nt] = __builtin_amdgcn_mfma_f32_16x16x32_bf16(af[mt], bf[nt], acc[mt][nt], 0, 0, 0);
  }

  #pragma unroll
  for (int mt = 0; mt < 4; ++mt) {
    #pragma unroll
    for (int r = 0; r < 4; ++r) {
      const int lrow = wr * 64 + mt * 16 + quad * 4 + r;
      const int grow = row0 + lrow;
      float s = 0.f, sq = 0.f;
      #pragma unroll
      for (int nt = 0; nt < 4; ++nt) {
        const int col = col0 + wc * 64 + nt * 16 + l16;
        float v = acc[mt][nt][r] + bias[col] + __bfloat162float(res[(size_t)grow * TCH + col]);
        Cout[(size_t)grow * TCH + col] = __float2bfloat16(v);
        s += v; sq += v * v;
      }
      #pragma unroll
      for (int off = 1; off < 16; off <<= 1) {
        s  += __shfl_xor(s,  off, 64);
        sq += __shfl_xor(sq, off, 64);
      }
      if (l16 == 0) { redS[lrow][wc] = s; redQ[lrow][wc] = sq; }
    }
  }
  __syncthreads();

  if (t < 128) {
    partial[(size_t)cb * MTOT + row0 + t] =
        make_float2(redS[t][0] + redS[t][1], redQ[t][0] + redQ[t][1]);
  }
}

// ---------------- LayerNorm from partials -----------------------------------
// 4096 blocks x 256 thr; one wave per row. Reads bf16 rows + per-row partials.
template<typename OUT_T>
__global__ __launch_bounds__(256) void ln_kernel(
    const __hip_bfloat16* __restrict__ Cin, const float2* __restrict__ partial,
    const float* __restrict__ gamma, const float* __restrict__ beta,
    OUT_T* __restrict__ out)
{
  const int t = threadIdx.x, wv = t >> 6, ln = t & 63;
  const int row = blockIdx.x * 4 + wv;

  float2 p0 = partial[row];
  float2 p1 = partial[MTOT + row];
  float2 p2 = partial[2 * MTOT + row];
  float2 p3 = partial[3 * MTOT + row];
  const float S = p0.x + p1.x + p2.x + p3.x;
  const float Q = p0.y + p1.y + p2.y + p3.y;
  const float mu  = S * (1.f / TCH);
  const float var = Q * (1.f / TCH) - mu * mu;
  const float rs  = rsqrtf(var + LN_EPS);

  const int c0 = ln * 8;
  bf16x8 vr = *reinterpret_cast<const bf16x8*>(Cin + (size_t)row * TCH + c0);
  float4 g0 = *(const float4*)(gamma + c0), g1 = *(const float4*)(gamma + c0 + 4);
  float4 b0 = *(const float4*)(beta  + c0), b1 = *(const float4*)(beta  + c0 + 4);

  float o[8];
  const float gg[8] = {g0.x,g0.y,g0.z,g0.w,g1.x,g1.y,g1.z,g1.w};
  const float bb[8] = {b0.x,b0.y,b0.z,b0.w,b1.x,b1.y,b1.z,b1.w};
  #pragma unroll
  for (int j = 0; j < 8; ++j) {
    union { __bf16 v; __hip_bfloat16 h; } u; u.v = vr[j];
    o[j] = (__bfloat162float(u.h) - mu) * rs * gg[j] + bb[j];
  }

  if constexpr (sizeof(OUT_T) == 2) {
    unsigned ov[4];
    #pragma unroll
    for (int j = 0; j < 4; ++j) ov[j] = pkbf(o[2*j], o[2*j+1]);
    *(uint4*)((__hip_bfloat16*)out + (size_t)row * TCH + c0) =
        make_uint4(ov[0], ov[1], ov[2], ov[3]);
  } else {
    float* op = (float*)out + (size_t)row * TCH + c0;
    *(float4*)op       = make_float4(o[0], o[1], o[2], o[3]);
    *(float4*)(op + 4) = make_float4(o[4], o[5], o[6], o[7]);
  }
}

// ---------------- host ------------------------------------------------------
extern "C" void kernel_launch(void* const* d_in, const int* in_sizes, int n_in,
                              void* d_out, int out_size, void* d_ws, size_t ws_size,
                              hipStream_t stream) {
  (void)in_sizes; (void)n_in; (void)out_size; (void)ws_size;
  const float* x     = (const float*)d_in[0];
  const float* wq    = (const float*)d_in[1];
  const float* bq    = (const float*)d_in[2];
  const float* wk    = (const float*)d_in[3];
  const float* bk    = (const float*)d_in[4];
  const float* wv    = (const float*)d_in[5];
  const float* bv    = (const float*)d_in[6];
  const float* wo    = (const float*)d_in[7];
  const float* bo    = (const float*)d_in[8];
  const float* w1    = (const float*)d_in[9];
  const float* b1    = (const float*)d_in[10];
  const float* w2    = (const float*)d_in[11];
  const float* b2    = (const float*)d_in[12];
  const float* gamma = (const float*)d_in[13];
  const float* beta  = (const float*)d_in[14];
  float* out = (float*)d_out;

  char* ws = (char*)d_ws;
  size_t off = 0;
  float4* q4      = (float4*)(ws + off); off += (size_t)MTOT * 16;
  uint4*  kvp     = (uint4*)(ws + off);  off += (size_t)MTOT * 16;
  float4* wo_eff4 = (float4*)(ws + off); off += (size_t)TCH * 16;
  float4* weff4   = (float4*)(ws + off); off += (size_t)TCH * 16;
  __hip_bfloat16* w2b   = (__hip_bfloat16*)(ws + off); off += (size_t)TCH * TCH * 2;
  __hip_bfloat16* wqkvb = (__hip_bfloat16*)(ws + off); off += (size_t)16 * TCH * 2;
  float*          qkvbias = (float*)(ws + off);        off += 64;
  __hip_bfloat16* r0b = (__hip_bfloat16*)(ws + off); off += (size_t)MTOT * TCH * 2;  // 16 MB
  __hip_bfloat16* r1b = (__hip_bfloat16*)(ws + off); off += (size_t)MTOT * TCH * 2;  // 16 MB
  __hip_bfloat16* rrb = (__hip_bfloat16*)(ws + off); off += (size_t)MTOT * TCH * 2;  // 16 MB
  float2* part2 = (float2*)(ws + off); off += (size_t)4 * MTOT * 8;                  // 512 KB

  prep_kernel<<<(TCH*TCH)/256, 256, 0, stream>>>(
      w2, wo, bo, wq, bq, wk, bk, wv, bv, w2b, wo_eff4, wqkvb, qkvbias);
  prep2_kernel<<<TCH/4, 256, 0, stream>>>(w1, b1, wo_eff4, weff4);
  qkv_kernel<<<MTOT/16, 256, 0, stream>>>(x, wqkvb, qkvbias, q4, kvp);
  // r0 = x + z @ weff^T + beff ; r1 = LN(r0)   (attention fused)
  attn_kernel<<<MTOT/64, 1024, 0, stream>>>(q4, kvp, x, weff4, gamma, beta, r0b, r1b);
  // rr = r0 + r1 @ w2^T + b2   (m97-structure GEMM, 2 blocks/CU)
  gemm_kernel<<<512, 256, 0, stream>>>(r1b, w2b, b2, r0b, rrb, part2);
  // out = LN(rr)
  ln_kernel<float><<<MTOT/4, 256, 0, stream>>>(rrb, part2, gamma, beta, out);
}